// Round 8
// baseline (215.271 us; speedup 1.0000x reference)
//
#include <hip/hip_runtime.h>
#include <math.h>

// ---------------- constants ----------------
// N=100 nodes, IN_C=65536, OUT_C=60, K=3 cheb, 2 heads, 1600 edges
#define KDIM    65536
#define NNODES  100
#define OUTC    60
#define YW      64          // padded col width of Y
#define YSLAB   (NNODES*YW) // 6400 floats per hk

// DMA GEMM chunking: BK=32 stage, 16 stages, slab 512
#define BK6     32
#define ITERS6  16
#define SLAB6   (BK6*ITERS6)    // 512 k per block
#define NKC6    (KDIM/SLAB6)    // 128
// f32 fallback GEMM chunking
#define CHUNK   256
#define NKC     256
#define STEPS   (CHUNK/32)

// ws layout (float offsets)
#define WS_S    0           // 10000 floats
#define WS_Y    10048       // 6*6400 = 38400 floats
#define WS_E    48448       // 2*6000 = 12000 floats (zero region ends here)
// bf16 x scratch (byte offsets)
#define XB_OFF_BYTES   245760ull                      // float offset 61440
#define XB_BYTES       (100ull*65536ull*2ull)         // 13107200
#define WS_NEED_BYTES  (XB_OFF_BYTES + XB_BYTES)      // 13352960

typedef short bf16x8 __attribute__((ext_vector_type(8)));
typedef float f32x4  __attribute__((ext_vector_type(4)));
typedef unsigned short ushort8 __attribute__((ext_vector_type(8)));

__device__ inline unsigned short f2bf(float f) {
    union { float f; unsigned u; } x; x.f = f;
    unsigned r = x.u + 0x7FFFu + ((x.u >> 16) & 1u);   // RNE (finite inputs)
    return (unsigned short)(r >> 16);
}

// ---------------- kernel 1: scatter S = -D^-1/2 A D^-1/2 (S pre-zeroed) --------
__global__ __launch_bounds__(256) void k_build_s(const int* __restrict__ ei,
                                                 float* __restrict__ S) {
    __shared__ int   deg[NNODES];
    __shared__ float dinv[NNODES];
    const int t = threadIdx.x;
    if (t < NNODES) deg[t] = 0;
    __syncthreads();
    const int* src = ei;
    const int* dst = ei + 1600;
    for (int e = t; e < 1600; e += 256) atomicAdd(&deg[src[e]], 1);
    __syncthreads();
    if (t < NNODES) { int d = deg[t]; dinv[t] = (d > 0) ? rsqrtf((float)d) : 0.f; }
    __syncthreads();
    for (int e = t; e < 1600; e += 256) {
        int s = src[e], d = dst[e];
        atomicAdd(&S[d * NNODES + s], -dinv[s] * dinv[d]);
    }
}

// ---------------- pass 1: x f32 -> bf16 (pure stream) --------------------------
__global__ __launch_bounds__(256) void k_cvt_x(const float* __restrict__ x,
                                               ushort8* __restrict__ xb) {
    int g = blockIdx.x * 256 + threadIdx.x;
    for (int i = g; i < 819200; i += 204800) {
        const float4 lo = ((const float4*)x)[2 * i];
        const float4 hi = ((const float4*)x)[2 * i + 1];
        ushort8 o;
        o[0] = f2bf(lo.x); o[1] = f2bf(lo.y); o[2] = f2bf(lo.z); o[3] = f2bf(lo.w);
        o[4] = f2bf(hi.x); o[5] = f2bf(hi.y); o[6] = f2bf(hi.z); o[7] = f2bf(hi.w);
        xb[i] = o;
    }
}

// ---------------- pass 2: single-pass DMA GEMM, BK=32, 5 blocks/CU -------------
// grid (6, 128) = 768 blocks, ALL co-resident at 29.7 KB LDS (5/CU capacity).
// block 256 = 4 waves = 4 n-tiles; each wave does all 7 m-tiles.
// K-loop: 16 iters of BK=32, double-buffered LDS, both operands via
// global_load_lds width-16 (1 KB/instr, zero VGPR): A 7 instrs, W 8 instrs/iter.
// More resident blocks per CU => one block's barrier drain is covered by the
// other blocks' compute/DMA issue (the round-7 structure at 2/CU could not).
__global__ __launch_bounds__(256) void k_gemm6(const unsigned short* __restrict__ xb,
                                               const float* __restrict__ wa,
                                               const float* __restrict__ wc,
                                               float* __restrict__ Y) {
    __shared__ unsigned short Ab[2][112 * BK6];   // 7168 B per buffer
    __shared__ float          Wf[2][BK6 * OUTC];  // 7680 B per buffer
    const int hk   = blockIdx.x;
    const int kc   = blockIdx.y;
    const int wave = threadIdx.x >> 6;
    const int lane = threadIdx.x & 63;
    const int n16  = lane & 15;
    const int quad = lane >> 4;
    const int c0   = wave * 16;
    const int cidx = min(c0 + n16, OUTC - 1);   // cols 60..63 junk -> pad cols of Y
    const int kb0  = kc * SLAB6;

    const float* Wg = (hk < 3 ? wa : wc) + (size_t)(hk % 3) * ((size_t)KDIM * OUTC);

    auto DMA = [&](int buf, int kb) {
        // A: 7 x 1KB instrs. Image chunk (16B) = j*64+lane at LDS base+lane*16;
        // source k-chunk XOR-swizzled: slot p of row m holds k-chunk p^(m&3).
        for (int j = wave; j < 7; j += 4) {
            int chunk = j * 64 + lane;
            int m  = chunk >> 2;               // 4 chunks per 32-k row
            int cc = (chunk & 3) ^ (m & 3);
            const unsigned short* src = xb + (size_t)min(m, NNODES - 1) * KDIM + kb + cc * 8;
            __builtin_amdgcn_global_load_lds(
                (const __attribute__((address_space(1))) void*)src,
                (__attribute__((address_space(3))) void*)&Ab[buf][j * 512], 16, 0, 0);
        }
        // W: raw f32 [32][60] chunk = 7680 contiguous bytes = 7 full + 1 half instr.
        const float* wsrc = Wg + (size_t)kb * OUTC;
        for (int j = wave; j < 8; j += 4) {
            if (j < 7 || lane < 32)
                __builtin_amdgcn_global_load_lds(
                    (const __attribute__((address_space(1))) void*)(wsrc + j * 256 + lane * 4),
                    (__attribute__((address_space(3))) void*)&Wf[buf][j * 256], 16, 0, 0);
        }
    };

    DMA(0, kb0);
    f32x4 acc[7] = {};

#pragma unroll
    for (int it = 0; it < ITERS6; ++it) {
        __syncthreads();                      // vmcnt drain: DMA(it) landed
        if (it + 1 < ITERS6) DMA((it + 1) & 1, kb0 + (it + 1) * BK6);
        const unsigned short* A = Ab[it & 1];
        const float*          B = Wf[it & 1];
        // B-frag: lane (n16,quad) needs W[quad*8+j][cidx], j=0..7.
        // quad-rotated j order -> disjoint bank windows (2-way = free).
        bf16x8 bfr;
#pragma unroll
        for (int j = 0; j < 8; ++j) {
            int jj = (j + quad * 2) & 7;
            bfr[jj] = (short)f2bf(B[(quad * 8 + jj) * OUTC + cidx]);
        }
        // A-frag: swizzled chunk (row&3 == n16&3)
        int ch = quad ^ (n16 & 3);
#pragma unroll
        for (int t = 0; t < 7; ++t) {
            bf16x8 afr = *(const bf16x8*)(A + (t * 16 + n16) * BK6 + ch * 8);
            acc[t] = __builtin_amdgcn_mfma_f32_16x16x32_bf16(afr, bfr, acc[t], 0, 0, 0);
        }
    }

    // D layout: col = lane&15, row = quad*4 + r within 16x16 tile
    float* Yb = Y + hk * YSLAB;
#pragma unroll
    for (int t = 0; t < 7; ++t)
#pragma unroll
        for (int r = 0; r < 4; ++r) {
            int row = t * 16 + quad * 4 + r;
            if (row < NNODES)
                atomicAdd(&Yb[row * YW + c0 + n16], acc[t][r]);
        }
}

// ---------------- fallback f32 GEMM (used only if ws is too small) -------------
__global__ __launch_bounds__(256, 2) void k_gemm_f32(const float* __restrict__ x,
                                                     const float* __restrict__ wa,
                                                     const float* __restrict__ wc,
                                                     float* __restrict__ Y) {
    const int hk   = blockIdx.x;
    const int kc   = blockIdx.y;
    const int wave = threadIdx.x >> 6;
    const int lane = threadIdx.x & 63;
    const int n16  = lane & 15;
    const int quad = lane >> 4;
    const float* W = (hk < 3 ? wa : wc) + (size_t)(hk % 3) * ((size_t)KDIM * OUTC);
    const int c0   = wave * 16;
    const int cidx = min(c0 + n16, OUTC - 1);
    const int kb0  = kc * CHUNK + quad * 8;
    const float* ap[7];
#pragma unroll
    for (int t = 0; t < 7; ++t)
        ap[t] = x + (size_t)min(n16 + 16 * t, NNODES - 1) * KDIM + kb0;
    const float* bp = W + (size_t)kb0 * OUTC + cidx;
    f32x4 acc[7] = {};
#pragma unroll 2
    for (int s = 0; s < STEPS; ++s) {
        bf16x8 bfr;
        const float* q = bp + (size_t)s * 32 * OUTC;
#pragma unroll
        for (int j = 0; j < 8; ++j) bfr[j] = (short)f2bf(q[j * OUTC]);
#pragma unroll
        for (int t = 0; t < 7; ++t) {
            const float* p = ap[t] + s * 32;
            float4 lo = *(const float4*)p;
            float4 hi = *(const float4*)(p + 4);
            bf16x8 afr;
            afr[0] = (short)f2bf(lo.x); afr[1] = (short)f2bf(lo.y);
            afr[2] = (short)f2bf(lo.z); afr[3] = (short)f2bf(lo.w);
            afr[4] = (short)f2bf(hi.x); afr[5] = (short)f2bf(hi.y);
            afr[6] = (short)f2bf(hi.z); afr[7] = (short)f2bf(hi.w);
            acc[t] = __builtin_amdgcn_mfma_f32_16x16x32_bf16(afr, bfr, acc[t], 0, 0, 0);
        }
    }
    float* Yb = Y + hk * YSLAB;
#pragma unroll
    for (int t = 0; t < 7; ++t)
#pragma unroll
        for (int r = 0; r < 4; ++r) {
            int row = t * 16 + quad * 4 + r;
            if (row < NNODES)
                atomicAdd(&Yb[row * YW + c0 + n16], acc[t][r]);
        }
}

// ---------------- kernel 3: emb = tanh(Y0 + S Y1 + 2 S(S Y2) - Y2 + b) + vnr ----
__global__ __launch_bounds__(128) void k_emb(const float* __restrict__ S,
                                             const float* __restrict__ Y,
                                             const float* __restrict__ vnr,
                                             const float* __restrict__ avw,
                                             const float* __restrict__ avb,
                                             const float* __restrict__ cvw,
                                             const float* __restrict__ cvb,
                                             const float* __restrict__ acb,
                                             const float* __restrict__ ccb,
                                             const float* __restrict__ afcb,
                                             const float* __restrict__ cfcb,
                                             float* __restrict__ E,
                                             float* __restrict__ out) {
    __shared__ float Sp[NNODES * 101];
    __shared__ float y0[NNODES], y1[NNODES], y2[NNODES], t2[NNODES];
    const int b = blockIdx.x, head = b / OUTC, c = b % OUTC;
    const int t = threadIdx.x;

    for (int i = t; i < NNODES * NNODES; i += 128)
        Sp[(i / NNODES) * 101 + (i % NNODES)] = S[i];
    const float* Yh = Y + (size_t)head * 3 * YSLAB;
    if (t < NNODES) {
        y0[t] = Yh[t * YW + c];
        y1[t] = Yh[YSLAB + t * YW + c];
        y2[t] = Yh[2 * YSLAB + t * YW + c];
    }
    if (b == 0 && t < 101) out[t] = (t < 100) ? afcb[t] : cfcb[0];
    __syncthreads();

    float z1 = 0.f, s2 = 0.f;
    if (t < NNODES) {
        const float* sr = Sp + t * 101;
        for (int m = 0; m < NNODES; ++m) { z1 += sr[m] * y1[m]; s2 += sr[m] * y2[m]; }
        t2[t] = s2;
    }
    __syncthreads();
    if (t < NNODES) {
        const float* sr = Sp + t * 101;
        float t3 = 0.f;
        for (int m = 0; m < NNODES; ++m) t3 += sr[m] * t2[m];
        const float* cb = head ? ccb : acb;
        const float* vw = head ? cvw : avw;
        const float* vb = head ? cvb : avb;
        float u  = y0[t] + z1 + 2.f * t3 - y2[t] + cb[c];
        float vs = vnr[0] * vw[c]        + vb[c]
                 + vnr[1] * vw[OUTC + c] + vb[OUTC + c]
                 + vnr[2] * vw[2*OUTC+c] + vb[2*OUTC+c];
        E[head * (NNODES * OUTC) + t * OUTC + c] = tanhf(u) + vs;
    }
}

// ---------------- kernel 4: heads — grid 240, 25 flat rows per block -----------
__global__ __launch_bounds__(128) void k_heads(const float* __restrict__ E,
                                               const float* __restrict__ afw,
                                               const float* __restrict__ cfw,
                                               float* __restrict__ out) {
    __shared__ float ea[25], ec[25];
    const int b = blockIdx.x, t = threadIdx.x;
    const int f0 = b * 25;
    if (t < 25) {
        ea[t] = E[f0 + t];
        ec[t] = E[NNODES * OUTC + f0 + t];
    }
    __syncthreads();
    if (t < 100) {
        float s = 0.f;
#pragma unroll
        for (int i = 0; i < 25; ++i) s += ea[i] * afw[(size_t)(f0 + i) * 100 + t];
        atomicAdd(&out[t], s);
    } else if (t == 100) {
        float s = 0.f;
#pragma unroll
        for (int i = 0; i < 25; ++i) s += ec[i] * cfw[f0 + i];
        atomicAdd(&out[100], s);
    }
}

// ---------------- launch ----------------
extern "C" void kernel_launch(void* const* d_in, const int* in_sizes, int n_in,
                              void* d_out, int out_size, void* d_ws, size_t ws_size,
                              hipStream_t stream) {
    const float* x    = (const float*)d_in[0];
    const int*   ei   = (const int*)  d_in[1];
    const float* vnr  = (const float*)d_in[2];
    const float* wa   = (const float*)d_in[3];
    const float* acb  = (const float*)d_in[4];
    const float* wc   = (const float*)d_in[5];
    const float* ccb  = (const float*)d_in[6];
    const float* avw  = (const float*)d_in[7];
    const float* avb  = (const float*)d_in[8];
    const float* cvw  = (const float*)d_in[9];
    const float* cvb  = (const float*)d_in[10];
    const float* afw  = (const float*)d_in[11];
    const float* afcb = (const float*)d_in[12];
    const float* cfw  = (const float*)d_in[13];
    const float* cfcb = (const float*)d_in[14];

    float* ws = (float*)d_ws;
    float* S  = ws + WS_S;
    float* Y  = ws + WS_Y;
    float* E  = ws + WS_E;
    float* out = (float*)d_out;

    hipMemsetAsync(ws, 0, (size_t)WS_E * sizeof(float), stream);  // zero S + Y
    k_build_s<<<1, 256, 0, stream>>>(ei, S);

    if (ws_size >= WS_NEED_BYTES) {
        unsigned short* xb = (unsigned short*)((char*)d_ws + XB_OFF_BYTES);
        k_cvt_x<<<800, 256, 0, stream>>>(x, (ushort8*)xb);
        k_gemm6<<<dim3(6, NKC6), 256, 0, stream>>>(xb, wa, wc, Y);
    } else {
        k_gemm_f32<<<dim3(6, NKC), 256, 0, stream>>>(x, wa, wc, Y);
    }

    k_emb<<<120, 128, 0, stream>>>(S, Y, vnr, avw, avb, cvw, cvb,
                                   acb, ccb, afcb, cfcb, E, out);
    k_heads<<<240, 128, 0, stream>>>(E, afw, cfw, out);
}